// Round 12
// baseline (290.047 us; speedup 1.0000x reference)
//
#include <hip/hip_runtime.h>

// SparseGCNPredicator on MI355X — all float tensors are f32.
// R23: occupancy bump on the agg kernels. R22 counters: k_aggemm 49us,
// occ 39%, FETCH 83MB (= fp8 table x ~6.5 cross-XCD L2 duplication,
// structural for random gathers), 2.0 TB/s effective. The miss path may be
// latency-limited at 39% occ -> raise TLP: launch_bounds(256,8) on
// k_aggemm/k_agg2 (8 blk/CU = 32 waves/CU; VGPR 44/36 <= 64 cap, no spill).
// Distinct from R18's null (per-lane ILP); this adds waves issuing
// independent misses. Everything else identical to R22 (best: 245.2us).
// R22: bin -> mid(csr|prepW2|gemm1) DAG split. R19: k_aggemm fusion.
// R15: transposed-MFMA epilogue. R14: A-frags global->reg. R12/13: agg/head.

typedef unsigned short ushort_t;
typedef unsigned int   uint_t;
typedef unsigned char  uchar_t;
typedef __attribute__((ext_vector_type(8))) short bf16x8;
typedef __attribute__((ext_vector_type(4))) float f32x4;
typedef __attribute__((ext_vector_type(2))) float f32x2;

#define EPB     4096   // edges per bin block
#define CAP2    32     // per-(block,bucket) slot capacity (Poisson mean 10.5; pow2)
#define BKT_CAP 8192   // per-bucket esrc segment (mean 4096)

__device__ __forceinline__ float bf2f(uint_t u) { return __uint_as_float(u << 16); }
__device__ __forceinline__ ushort_t f2bf(float f) {
  uint_t x = __float_as_uint(f);
  x = x + 0x7fffu + ((x >> 16) & 1u);   // round-to-nearest-even
  return (ushort_t)(x >> 16);
}

__device__ __forceinline__ bf16x8 pack8(float4 u, float4 v) {
  union { uint4 q; bf16x8 b; } cv;
  cv.q.x = (uint_t)f2bf(u.x) | ((uint_t)f2bf(u.y) << 16);
  cv.q.y = (uint_t)f2bf(u.z) | ((uint_t)f2bf(u.w) << 16);
  cv.q.z = (uint_t)f2bf(v.x) | ((uint_t)f2bf(v.y) << 16);
  cv.q.w = (uint_t)f2bf(v.z) | ((uint_t)f2bf(v.w) << 16);
  return cv.b;
}

// ---------------- k_bin: bucket-major coalesced binning ----------------
__global__ __launch_bounds__(256) void k_bin(const int* __restrict__ src, const int* __restrict__ dst,
                                             uint_t* __restrict__ binbuf, int* __restrict__ cntmatT,
                                             int E, int nblk, int nbkt) {
  __shared__ int cur[512];
  int t = threadIdx.x, bid = blockIdx.x;
  for (int r = t; r < nbkt; r += 256) cur[r] = 0;
  __syncthreads();
  int base = bid * EPB;
#pragma unroll
  for (int j = 0; j < EPB / 256; j++) {
    int e = base + j * 256 + t;
    if (e < E) {
      int s = src[e], d = dst[e];
      int b = d >> 8;
      int p = atomicAdd(&cur[b], 1);
      if (p < CAP2)
        binbuf[((size_t)b * nblk + bid) * CAP2 + p] = (uint_t)s | ((uint_t)(d & 255) << 17);
    }
  }
  __syncthreads();
  for (int r = t; r < nbkt; r += 256) {
    int c = cur[r];
    cntmatT[(size_t)r * nblk + bid] = (c < CAP2) ? c : CAP2;
  }
}

// ---------------- k_mid: csr (blocks <nbkt) | prepW2 (32) | gemm1 — 512 threads ----------------
__global__ __launch_bounds__(512) void k_mid(const uint_t* __restrict__ binbuf, const int* __restrict__ cntmatT,
                                             int* __restrict__ esrc, int* __restrict__ deg,
                                             int* __restrict__ offs, float* __restrict__ nrm,
                                             const float* __restrict__ X, const float* __restrict__ W1,
                                             const float* __restrict__ b1, uchar_t* __restrict__ Yf8,
                                             uchar_t* __restrict__ YfC,
                                             const float* __restrict__ W2, ushort_t* __restrict__ Wf2,
                                             int N, int nblk, int nbkt, int GB1m) {
  __shared__ union {
    struct {
      int cnt_s[512];
      int hist[256];
      int cur[256];
      int wsum[4];
      int lsrc[BKT_CAP];
    } c;                           // 36.9 KB (csr role)
    ushort_t Ws[16384];            // 32 KB (gemm role)
  } S;
  int t = threadIdx.x;
  int bid = blockIdx.x;

  if (bid < nbkt) {                // -------- csr --------
    int b = bid;
    if (b == 0 && t == 0) nrm[N] = 0.f;   // tail-clamp slot: scale 0
    int n0 = b << 8;
    int gbase = b * BKT_CAP;
    for (int r = t; r < nblk; r += 512) S.c.cnt_s[r] = cntmatT[(size_t)b * nblk + r];
    if (t < 256) S.c.hist[t] = 0;
    __syncthreads();
    const uint4* seg4 = (const uint4*)(binbuf + (size_t)b * nblk * CAP2);
    int total4 = (nblk * CAP2) >> 2;
    for (int i4 = t; i4 < total4; i4 += 512) {
      int base = i4 << 2;
      int c = S.c.cnt_s[base >> 5];
      int s0 = base & 31;
      if (s0 < c) {
        uint4 v = seg4[i4];
        int nv = c - s0;
        atomicAdd(&S.c.hist[v.x >> 17], 1);
        if (nv > 1) atomicAdd(&S.c.hist[v.y >> 17], 1);
        if (nv > 2) atomicAdd(&S.c.hist[v.z >> 17], 1);
        if (nv > 3) atomicAdd(&S.c.hist[v.w >> 17], 1);
      }
    }
    __syncthreads();
    int lane = t & 63, wv = t >> 6;
    if (t < 256) {
      int h = S.c.hist[t];
      int incl = h;
#pragma unroll
      for (int s = 1; s < 64; s <<= 1) {
        int x = __shfl_up(incl, s, 64);
        if (lane >= s) incl += x;
      }
      if (lane == 63) S.c.wsum[wv] = incl;
      __syncthreads();
      int wbase = 0;
#pragma unroll
      for (int k = 0; k < 4; k++) wbase += (k < wv) ? S.c.wsum[k] : 0;
      int excl = wbase + incl - h;
      S.c.cur[t] = excl;
      int node = n0 + t;
      if (node < N) {
        deg[node] = h;
        offs[node] = gbase + excl;
        nrm[node] = (h > 0) ? rsqrtf((float)h) : 0.f;
      }
    } else {
      __syncthreads();
    }
    __syncthreads();
    int count = S.c.wsum[0] + S.c.wsum[1] + S.c.wsum[2] + S.c.wsum[3];
    for (int i4 = t; i4 < total4; i4 += 512) {
      int base = i4 << 2;
      int c = S.c.cnt_s[base >> 5];
      int s0 = base & 31;
      if (s0 < c) {
        uint4 v = seg4[i4];
        int nv = c - s0;
        { int p = atomicAdd(&S.c.cur[v.x >> 17], 1); S.c.lsrc[p] = (int)(v.x & 0x1ffffu); }
        if (nv > 1) { int p = atomicAdd(&S.c.cur[v.y >> 17], 1); S.c.lsrc[p] = (int)(v.y & 0x1ffffu); }
        if (nv > 2) { int p = atomicAdd(&S.c.cur[v.z >> 17], 1); S.c.lsrc[p] = (int)(v.z & 0x1ffffu); }
        if (nv > 3) { int p = atomicAdd(&S.c.cur[v.w >> 17], 1); S.c.lsrc[p] = (int)(v.w & 0x1ffffu); }
      }
    }
    __syncthreads();
    for (int i = t; i < count; i += 512) esrc[gbase + i] = S.c.lsrc[i];
    return;
  }
  if (bid < nbkt + 32) {           // -------- prepW2 + zero fp8 row N (both buffers) --------
    if (bid == nbkt && t < 8)  ((uint4*)Yf8)[(size_t)N * 8 + t] = make_uint4(0u, 0u, 0u, 0u);
    if (bid == nbkt && t >= 8 && t < 16)
      ((uint4*)YfC)[(size_t)N * 8 + (t - 8)] = make_uint4(0u, 0u, 0u, 0u);
    int idx = (bid - nbkt) * 512 + t;
    int n = idx & 127, k = idx >> 7;
    Wf2[((size_t)(k >> 3) * 128 + n) * 8 + (k & 7)] = f2bf(W2[(size_t)k * 128 + n]);
    return;
  }

  // -------- gemm1: Yf8[r] = fp8( (X[r] @ W1 + b1) * 16 ), 256-row tile, 8 waves --------
  {  // convert W1 (f32 row-major [k][n]) into Ws layout [(q*128+n)*8+j]
    const float4* W4 = (const float4*)W1;
#pragma unroll
    for (int i = 0; i < 8; i++) {
      int idx = i * 512 + t;
      int k = idx >> 5;
      int n0 = (idx & 31) * 4;
      float4 v = W4[idx];
      int qb = k >> 3, j = k & 7;
      S.Ws[((size_t)qb * 128 + n0 + 0) * 8 + j] = f2bf(v.x);
      S.Ws[((size_t)qb * 128 + n0 + 1) * 8 + j] = f2bf(v.y);
      S.Ws[((size_t)qb * 128 + n0 + 2) * 8 + j] = f2bf(v.z);
      S.Ws[((size_t)qb * 128 + n0 + 3) * 8 + j] = f2bf(v.w);
    }
  }
  int r0 = (bid - nbkt - 32) * 256;
  int wave = t >> 6, lane = t & 63;      // wave 0..7
  int ln = lane & 15, quad = lane >> 4;
  int row0 = r0 + wave * 32 + ln;
  int row1 = row0 + 16;
  int cr0 = min(row0, N - 1);
  int cr1 = min(row1, N - 1);

  bf16x8 a0[4], a1[4];
  {
    const float4* Xp = (const float4*)X;
#pragma unroll
    for (int kc = 0; kc < 4; kc++) {
      int q = kc * 4 + quad;
      float4 u0 = Xp[(size_t)cr0 * 32 + q * 2];
      float4 v0 = Xp[(size_t)cr0 * 32 + q * 2 + 1];
      float4 u1 = Xp[(size_t)cr1 * 32 + q * 2];
      float4 v1 = Xp[(size_t)cr1 * 32 + q * 2 + 1];
      a0[kc] = pack8(u0, v0);
      a1[kc] = pack8(u1, v1);
    }
  }
  __syncthreads();

  const bf16x8* Wb = (const bf16x8*)S.Ws;
  f32x4 acc[2][8];
#pragma unroll
  for (int mt = 0; mt < 2; mt++)
#pragma unroll
    for (int ct = 0; ct < 8; ct++) acc[mt][ct] = (f32x4){0.f, 0.f, 0.f, 0.f};

#pragma unroll
  for (int kc = 0; kc < 4; kc++) {
    int q = kc * 4 + quad;
#pragma unroll
    for (int ct = 0; ct < 8; ct++) {
      bf16x8 b = Wb[q * 128 + ct * 16 + ln];
      // swapped operands: lane holds 4 consecutive channels of one node row
      acc[0][ct] = __builtin_amdgcn_mfma_f32_16x16x32_bf16(b, a0[kc], acc[0][ct], 0, 0, 0);
      acc[1][ct] = __builtin_amdgcn_mfma_f32_16x16x32_bf16(b, a1[kc], acc[1][ct], 0, 0, 0);
    }
  }

  int chbase = quad * 4;
  float4 bs[8];
#pragma unroll
  for (int ct = 0; ct < 8; ct++) bs[ct] = *(const float4*)(b1 + ct * 16 + chbase);
  uint_t* Y32 = (uint_t*)Yf8;
  if (row0 < N) {
#pragma unroll
    for (int ct = 0; ct < 8; ct++) {
      f32x4 v = acc[0][ct];
      float x0 = (v[0] + bs[ct].x) * 16.f, x1 = (v[1] + bs[ct].y) * 16.f;
      float x2 = (v[2] + bs[ct].z) * 16.f, x3 = (v[3] + bs[ct].w) * 16.f;
      int w = __builtin_amdgcn_cvt_pk_fp8_f32(x0, x1, 0, false);
      w = __builtin_amdgcn_cvt_pk_fp8_f32(x2, x3, w, true);
      Y32[(size_t)row0 * 32 + ct * 4 + quad] = (uint_t)w;
    }
  }
  if (row1 < N) {
#pragma unroll
    for (int ct = 0; ct < 8; ct++) {
      f32x4 v = acc[1][ct];
      float x0 = (v[0] + bs[ct].x) * 16.f, x1 = (v[1] + bs[ct].y) * 16.f;
      float x2 = (v[2] + bs[ct].z) * 16.f, x3 = (v[3] + bs[ct].w) * 16.f;
      int w = __builtin_amdgcn_cvt_pk_fp8_f32(x0, x1, 0, false);
      w = __builtin_amdgcn_cvt_pk_fp8_f32(x2, x3, w, true);
      Y32[(size_t)row1 * 32 + ct * 4 + quad] = (uint_t)w;
    }
  }
}

// ---------------- agg helpers ----------------
__device__ __forceinline__ void acc16p(f32x2* a, uint4 g) {
  a[0] += __builtin_amdgcn_cvt_pk_f32_fp8((int)g.x, false);
  a[1] += __builtin_amdgcn_cvt_pk_f32_fp8((int)g.x, true);
  a[2] += __builtin_amdgcn_cvt_pk_f32_fp8((int)g.y, false);
  a[3] += __builtin_amdgcn_cvt_pk_f32_fp8((int)g.y, true);
  a[4] += __builtin_amdgcn_cvt_pk_f32_fp8((int)g.z, false);
  a[5] += __builtin_amdgcn_cvt_pk_f32_fp8((int)g.z, true);
  a[6] += __builtin_amdgcn_cvt_pk_f32_fp8((int)g.w, false);
  a[7] += __builtin_amdgcn_cvt_pk_f32_fp8((int)g.w, true);
}
__device__ __forceinline__ void acc16f(f32x2* a, uint4 g, float s) {
  f32x2 sv = {s, s};
  a[0] += __builtin_amdgcn_cvt_pk_f32_fp8((int)g.x, false) * sv;
  a[1] += __builtin_amdgcn_cvt_pk_f32_fp8((int)g.x, true)  * sv;
  a[2] += __builtin_amdgcn_cvt_pk_f32_fp8((int)g.y, false) * sv;
  a[3] += __builtin_amdgcn_cvt_pk_f32_fp8((int)g.y, true)  * sv;
  a[4] += __builtin_amdgcn_cvt_pk_f32_fp8((int)g.z, false) * sv;
  a[5] += __builtin_amdgcn_cvt_pk_f32_fp8((int)g.z, true)  * sv;
  a[6] += __builtin_amdgcn_cvt_pk_f32_fp8((int)g.w, false) * sv;
  a[7] += __builtin_amdgcn_cvt_pk_f32_fp8((int)g.w, true)  * sv;
}
__device__ __forceinline__ uint_t pk2(f32x2 v, float nv) {
  float a = fmaxf(v.x * nv, 0.f);
  float b = fmaxf(v.y * nv, 0.f);
  return (uint_t)f2bf(a) | ((uint_t)f2bf(b) << 16);
}

// ---------------- Fused agg1 + gemm2 ----------------
__global__ __launch_bounds__(256, 8) void k_aggemm(const uint4* __restrict__ hn8, const int* __restrict__ offs,
                                                   const int* __restrict__ deg, const float* __restrict__ nrm,
                                                   const int* __restrict__ esrc, const ushort_t* __restrict__ Wf2,
                                                   const float* __restrict__ b2, uchar_t* __restrict__ YfC,
                                                   int N) {
  __shared__ uint4 Hs[32 * 17];    // 32 rows x (16 chunks + 1 pad) = 8704 B
  int wave = threadIdx.x >> 6, lane = threadIdx.x & 63;
  int sub = lane >> 3, sl = lane & 7;
  int base = blockIdx.x * 32;
  int node = base + wave * 8 + sub;
  bool live = node < N;
  int d  = live ? deg[node] : 0;
  int eb = live ? offs[node] : 0;
  int maxd = d;
  maxd = max(maxd, __shfl_xor(maxd, 8, 64));
  maxd = max(maxd, __shfl_xor(maxd, 16, 64));
  maxd = max(maxd, __shfl_xor(maxd, 32, 64));
  f32x2 A[8] = {};
  f32x2 B[8] = {};
  int it = 0;
  for (; it + 4 <= maxd; it += 4) {
    int x0 = esrc[eb + it];
    int x1 = esrc[eb + it + 1];
    int x2 = esrc[eb + it + 2];
    int x3 = esrc[eb + it + 3];
    x0 = (it < d) ? x0 : N;          // clamped: row N zero, nrm[N]=0
    x1 = (it + 1 < d) ? x1 : N;
    x2 = (it + 2 < d) ? x2 : N;
    x3 = (it + 3 < d) ? x3 : N;
    uint4 g0 = hn8[(size_t)x0 * 8 + sl];
    uint4 g1 = hn8[(size_t)x1 * 8 + sl];
    uint4 g2 = hn8[(size_t)x2 * 8 + sl];
    uint4 g3 = hn8[(size_t)x3 * 8 + sl];
    float s0 = nrm[x0], s1 = nrm[x1], s2 = nrm[x2], s3 = nrm[x3];
    acc16f(A, g0, s0); acc16f(B, g1, s1);
    acc16f(A, g2, s2); acc16f(B, g3, s3);
  }
  for (; it < maxd; it += 2) {
    int x0 = esrc[eb + it];
    int x1 = esrc[eb + it + 1];
    x0 = (it < d) ? x0 : N;
    x1 = (it + 1 < d) ? x1 : N;
    uint4 g0 = hn8[(size_t)x0 * 8 + sl];
    uint4 g1 = hn8[(size_t)x1 * 8 + sl];
    float s0 = nrm[x0], s1 = nrm[x1];
    acc16f(A, g0, s0); acc16f(B, g1, s1);
  }
  float nv = nrm[live ? node : N] * 0.0625f;
  uint4 p0, p1;
  p0.x = pk2(A[0] + B[0], nv); p0.y = pk2(A[1] + B[1], nv);
  p0.z = pk2(A[2] + B[2], nv); p0.w = pk2(A[3] + B[3], nv);
  p1.x = pk2(A[4] + B[4], nv); p1.y = pk2(A[5] + B[5], nv);
  p1.z = pk2(A[6] + B[6], nv); p1.w = pk2(A[7] + B[7], nv);
  int lrow = wave * 8 + sub;
  Hs[lrow * 17 + sl * 2]     = p0;
  Hs[lrow * 17 + sl * 2 + 1] = p1;
  __syncthreads();

  // Phase B: rows base..base+31, wave owns ct = wave*2 + {0,1}
  int ln = lane & 15, quad = lane >> 4;
  const bf16x8* Wb = (const bf16x8*)Wf2;
  f32x4 acc[2][2];
#pragma unroll
  for (int mt = 0; mt < 2; mt++)
#pragma unroll
    for (int c = 0; c < 2; c++) acc[mt][c] = (f32x4){0.f, 0.f, 0.f, 0.f};
#pragma unroll
  for (int kc = 0; kc < 4; kc++) {
    int q = kc * 4 + quad;
    union { uint4 u; bf16x8 b; } a0, a1;
    a0.u = Hs[ln * 17 + q];
    a1.u = Hs[(16 + ln) * 17 + q];
    bf16x8 b0 = Wb[q * 128 + (wave * 2 + 0) * 16 + ln];
    bf16x8 b1 = Wb[q * 128 + (wave * 2 + 1) * 16 + ln];
    acc[0][0] = __builtin_amdgcn_mfma_f32_16x16x32_bf16(b0, a0.b, acc[0][0], 0, 0, 0);
    acc[1][0] = __builtin_amdgcn_mfma_f32_16x16x32_bf16(b0, a1.b, acc[1][0], 0, 0, 0);
    acc[0][1] = __builtin_amdgcn_mfma_f32_16x16x32_bf16(b1, a0.b, acc[0][1], 0, 0, 0);
    acc[1][1] = __builtin_amdgcn_mfma_f32_16x16x32_bf16(b1, a1.b, acc[1][1], 0, 0, 0);
  }
  uint_t* Y32 = (uint_t*)YfC;
#pragma unroll
  for (int mt = 0; mt < 2; mt++) {
    int row = base + mt * 16 + ln;
    int crw = min(row, N);           // nrm has N+1 entries
    float nvr = nrm[crw] * 16.f;
#pragma unroll
    for (int c = 0; c < 2; c++) {
      int ct = wave * 2 + c;
      float4 bs = *(const float4*)(b2 + ct * 16 + quad * 4);
      f32x4 v = acc[mt][c];
      float x0 = (v[0] + bs.x) * nvr, x1 = (v[1] + bs.y) * nvr;
      float x2 = (v[2] + bs.z) * nvr, x3 = (v[3] + bs.w) * nvr;
      int w = __builtin_amdgcn_cvt_pk_fp8_f32(x0, x1, 0, false);
      w = __builtin_amdgcn_cvt_pk_fp8_f32(x2, x3, w, true);
      if (row < N) Y32[(size_t)row * 32 + ct * 4 + quad] = (uint_t)w;
    }
  }
}

// ---------------- Agg layer 2: outb[i] = bf16(relu(nrm_i/16 * sum_e hn2[s])) ----------------
__global__ __launch_bounds__(256, 8) void k_agg2(const uint4* __restrict__ hn8, const int* __restrict__ offs,
                                                 const int* __restrict__ deg, const float* __restrict__ nrm,
                                                 const int* __restrict__ esrc, uint4* __restrict__ outb, int N) {
  int wave = threadIdx.x >> 6, lane = threadIdx.x & 63;
  int sub = lane >> 3, sl = lane & 7;
  int node = blockIdx.x * 32 + wave * 8 + sub;
  bool live = node < N;
  int d  = live ? deg[node] : 0;
  int eb = live ? offs[node] : 0;
  int maxd = d;
  maxd = max(maxd, __shfl_xor(maxd, 8, 64));
  maxd = max(maxd, __shfl_xor(maxd, 16, 64));
  maxd = max(maxd, __shfl_xor(maxd, 32, 64));
  f32x2 A[8] = {};
  f32x2 B[8] = {};
  int it = 0;
  for (; it + 4 <= maxd; it += 4) {
    int x0 = esrc[eb + it];
    int x1 = esrc[eb + it + 1];
    int x2 = esrc[eb + it + 2];
    int x3 = esrc[eb + it + 3];
    x0 = (it < d) ? x0 : N;
    x1 = (it + 1 < d) ? x1 : N;
    x2 = (it + 2 < d) ? x2 : N;
    x3 = (it + 3 < d) ? x3 : N;
    uint4 g0 = hn8[(size_t)x0 * 8 + sl];
    uint4 g1 = hn8[(size_t)x1 * 8 + sl];
    uint4 g2 = hn8[(size_t)x2 * 8 + sl];
    uint4 g3 = hn8[(size_t)x3 * 8 + sl];
    acc16p(A, g0); acc16p(B, g1);
    acc16p(A, g2); acc16p(B, g3);
  }
  for (; it < maxd; it += 2) {
    int x0 = esrc[eb + it];
    int x1 = esrc[eb + it + 1];
    x0 = (it < d) ? x0 : N;
    x1 = (it + 1 < d) ? x1 : N;
    uint4 g0 = hn8[(size_t)x0 * 8 + sl];
    uint4 g1 = hn8[(size_t)x1 * 8 + sl];
    acc16p(A, g0); acc16p(B, g1);
  }
  if (!live) return;
  float nv = nrm[node] * 0.0625f;
  uint4 p0, p1;
  p0.x = pk2(A[0] + B[0], nv); p0.y = pk2(A[1] + B[1], nv);
  p0.z = pk2(A[2] + B[2], nv); p0.w = pk2(A[3] + B[3], nv);
  p1.x = pk2(A[4] + B[4], nv); p1.y = pk2(A[5] + B[5], nv);
  p1.z = pk2(A[6] + B[6], nv); p1.w = pk2(A[7] + B[7], nv);
  outb[(size_t)node * 16 + sl * 2]     = p0;
  outb[(size_t)node * 16 + sl * 2 + 1] = p1;
}

// ---------------- Head: segmented mean over sorted gidx -> FC(relu) -> dot(Wout)+bout ----------------
__device__ __forceinline__ int lowerb(const int* __restrict__ a, int n, int v) {
  int lo = 0, hi = n;
  while (lo < hi) { int m = (lo + hi) >> 1; if (a[m] < v) lo = m + 1; else hi = m; }
  return lo;
}

__global__ __launch_bounds__(256) void k_head(const ushort_t* __restrict__ h2, const int* __restrict__ gidx,
                                              const float* __restrict__ Wfc, const float* __restrict__ bfc,
                                              const float* __restrict__ Wout, const float* __restrict__ bout,
                                              float* __restrict__ out, int N) {
  __shared__ float partial[4][128];
  __shared__ float pv[128];
  __shared__ float fcp[2][128];
  __shared__ float red[128];
  __shared__ int segb[2];
  int g = blockIdx.x, t = threadIdx.x;
  int wave = t >> 6, lane = t & 63;
  if (t == 0)  segb[0] = lowerb(gidx, N, g);
  if (t == 64) segb[1] = lowerb(gidx, N, g + 1);
  __syncthreads();
  int lo = segb[0], hi = segb[1];
  int q = lane & 15;
  int r4 = lane >> 4;
  const uint4* h4 = (const uint4*)h2;
  f32x2 A[4] = {};
  for (int i = lo + wave * 4 + r4; i < hi; i += 16) {
    uint4 v = h4[(size_t)i * 16 + q];
    A[0] += (f32x2){__uint_as_float(v.x << 16), __uint_as_float(v.x & 0xffff0000u)};
    A[1] += (f32x2){__uint_as_float(v.y << 16), __uint_as_float(v.y & 0xffff0000u)};
    A[2] += (f32x2){__uint_as_float(v.z << 16), __uint_as_float(v.z & 0xffff0000u)};
    A[3] += (f32x2){__uint_as_float(v.w << 16), __uint_as_float(v.w & 0xffff0000u)};
  }
#pragma unroll
  for (int k = 0; k < 4; k++) {
    A[k].x += __shfl_xor(A[k].x, 16, 64); A[k].y += __shfl_xor(A[k].y, 16, 64);
    A[k].x += __shfl_xor(A[k].x, 32, 64); A[k].y += __shfl_xor(A[k].y, 32, 64);
  }
  if (lane < 16) {
    partial[wave][q * 8 + 0] = A[0].x; partial[wave][q * 8 + 1] = A[0].y;
    partial[wave][q * 8 + 2] = A[1].x; partial[wave][q * 8 + 3] = A[1].y;
    partial[wave][q * 8 + 4] = A[2].x; partial[wave][q * 8 + 5] = A[2].y;
    partial[wave][q * 8 + 6] = A[3].x; partial[wave][q * 8 + 7] = A[3].y;
  }
  __syncthreads();
  if (t < 128) {
    float c = (float)(hi - lo); if (c < 1.f) c = 1.f;
    float s = (partial[0][t] + partial[1][t]) + (partial[2][t] + partial[3][t]);
    pv[t] = s / c;
  }
  __syncthreads();
  int col = t & 127, half = t >> 7;
  float acc = (half == 0) ? bfc[col] : 0.f;
  const float* Wc = Wfc + (size_t)half * 64 * 128 + col;
#pragma unroll 8
  for (int k = 0; k < 64; k++) acc += pv[half * 64 + k] * Wc[k * 128];
  fcp[half][col] = acc;
  __syncthreads();
  if (t < 128) {
    float a = fmaxf(fcp[0][t] + fcp[1][t], 0.f);
    red[t] = a * Wout[t];
  }
  __syncthreads();
  if (t < 64) {
    float v2 = red[t] + red[t + 64];
#pragma unroll
    for (int s = 32; s > 0; s >>= 1) v2 += __shfl_xor(v2, s, 64);
    if (t == 0) out[g] = v2 + bout[0];
  }
}

// ---------------- launch ----------------

extern "C" void kernel_launch(void* const* d_in, const int* in_sizes, int n_in,
                              void* d_out, int out_size, void* d_ws, size_t ws_size,
                              hipStream_t stream) {
  const float* X    = (const float*)d_in[0];
  const int*   adj  = (const int*)d_in[1];
  const int*   gidx = (const int*)d_in[2];
  // d_in[3] = is_training (ignored; dropout rate is 0)
  const float* W1   = (const float*)d_in[4];
  const float* b1   = (const float*)d_in[5];
  const float* W2   = (const float*)d_in[6];
  const float* b2   = (const float*)d_in[7];
  const float* Wfc  = (const float*)d_in[8];
  const float* bfc  = (const float*)d_in[9];
  const float* Wout = (const float*)d_in[10];
  const float* bout = (const float*)d_in[11];
  (void)n_in; (void)ws_size;

  const int N = in_sizes[2];        // 100000
  const int E = in_sizes[1] / 2;    // 1600000
  const int G = out_size;           // 1024 (OUT=1)
  const int* srcv = adj;
  const int* dstv = adj + E;
  const int nbkt = (N + 255) >> 8;            // 391 buckets of 256 nodes
  const int nblk = (E + EPB - 1) / EPB;       // 391 bin blocks
  const int GB1m = (N + 255) / 256;           // 391 gemm1 blocks (256-row tiles)

  char* w = (char*)d_ws;
  size_t off = 0;
  auto alloc = [&](size_t bytes) -> void* {
    void* p = (void*)(w + off);
    off += (bytes + 255) & ~(size_t)255;
    return p;
  };
  uchar_t*  bufA  = (uchar_t*)alloc((size_t)(N + 1) * 128);                // hn1 fp8 + zero row N
  uchar_t*  bufC  = (uchar_t*)alloc((size_t)(N + 1) * 128);                // hn2 fp8 + zero row N
  ushort_t* bufB  = (ushort_t*)alloc((size_t)N * 128 * sizeof(ushort_t));  // h2 (bf16)
  float*    nrm   = (float*)alloc((size_t)(N + 1) * sizeof(float));        // +1: nrm[N]=0
  int*      deg   = (int*)alloc((size_t)N * sizeof(int));
  int*      offs  = (int*)alloc((size_t)N * sizeof(int));
  int*      esrc  = (int*)alloc(((size_t)nbkt * BKT_CAP + BKT_CAP) * sizeof(int));  // + slack
  uint_t*   binb  = (uint_t*)alloc((size_t)nbkt * nblk * CAP2 * sizeof(uint_t));
  int*      cmatT = (int*)alloc((size_t)nbkt * nblk * sizeof(int));        // bucket-major
  ushort_t* Wf2   = (ushort_t*)alloc((size_t)128 * 128 * sizeof(ushort_t));

  // stage 1: bin alone (csr's only dependency)
  k_bin<<<nblk, 256, 0, stream>>>(srcv, dstv, binb, cmatT, E, nblk, nbkt);
  // stage 2: csr | prepW2 | gemm1 overlapped (csr blocks dispatched first)
  k_mid<<<nbkt + 32 + GB1m, 512, 0, stream>>>(binb, cmatT, esrc, deg, offs, nrm,
                                              X, W1, b1, bufA, bufC, W2, Wf2,
                                              N, nblk, nbkt, GB1m);

  const int aggGrid = (N + 31) / 32;
  // fused agg1 + gemm2: bufA -> (h1 in LDS) -> bufC (fp8)
  k_aggemm<<<aggGrid, 256, 0, stream>>>((const uint4*)bufA, offs, deg, nrm, esrc,
                                        Wf2, b2, bufC, N);
  // agg2: bufC -> bufB (h2 bf16)
  k_agg2<<<aggGrid, 256, 0, stream>>>((const uint4*)bufC, offs, deg, nrm, esrc, (uint4*)bufB, N);
  k_head<<<G, 256, 0, stream>>>(bufB, gidx, Wfc, bfc, Wout, bout, (float*)d_out, N);
}

// Round 13
// 245.131 us; speedup vs baseline: 1.1832x; 1.1832x over previous
//
#include <hip/hip_runtime.h>

// SparseGCNPredicator on MI355X — all float tensors are f32.
// R24: REVERT to R22 (best, 245.2us). R23 post-mortem: launch_bounds(256,8)
// on the aggs raised occupancy 40->63% but the extra concurrent random
// gathers THRASHED the per-XCD L2s: FETCH 83->165MB, WRITE 12.5->72MB,
// agg2 44->70us, total 290us. With R18 (4-deep ILP: null) this maps the agg
// concurrency curve: ~40% occ is the optimum of L2-reuse vs latency-hiding;
// the gather path is throughput-saturated at ~2TB/s / 83MB structural
// cross-XCD traffic there. Agg levers exhausted (fusion won; ILP/TLP did
// not). R22: bin -> mid(csr|prepW2|gemm1) DAG split. R19: k_aggemm fusion
// (agg1+gemm2 via LDS h1). R18: 4-edge unroll. R15: transposed-MFMA
// epilogue. R14: A-frags global->reg. R13: k_head uint4. R12: 8-nodes/wave.

typedef unsigned short ushort_t;
typedef unsigned int   uint_t;
typedef unsigned char  uchar_t;
typedef __attribute__((ext_vector_type(8))) short bf16x8;
typedef __attribute__((ext_vector_type(4))) float f32x4;
typedef __attribute__((ext_vector_type(2))) float f32x2;

#define EPB     4096   // edges per bin block
#define CAP2    32     // per-(block,bucket) slot capacity (Poisson mean 10.5; pow2)
#define BKT_CAP 8192   // per-bucket esrc segment (mean 4096)

__device__ __forceinline__ float bf2f(uint_t u) { return __uint_as_float(u << 16); }
__device__ __forceinline__ ushort_t f2bf(float f) {
  uint_t x = __float_as_uint(f);
  x = x + 0x7fffu + ((x >> 16) & 1u);   // round-to-nearest-even
  return (ushort_t)(x >> 16);
}

__device__ __forceinline__ bf16x8 pack8(float4 u, float4 v) {
  union { uint4 q; bf16x8 b; } cv;
  cv.q.x = (uint_t)f2bf(u.x) | ((uint_t)f2bf(u.y) << 16);
  cv.q.y = (uint_t)f2bf(u.z) | ((uint_t)f2bf(u.w) << 16);
  cv.q.z = (uint_t)f2bf(v.x) | ((uint_t)f2bf(v.y) << 16);
  cv.q.w = (uint_t)f2bf(v.z) | ((uint_t)f2bf(v.w) << 16);
  return cv.b;
}

// ---------------- k_bin: bucket-major coalesced binning ----------------
__global__ __launch_bounds__(256) void k_bin(const int* __restrict__ src, const int* __restrict__ dst,
                                             uint_t* __restrict__ binbuf, int* __restrict__ cntmatT,
                                             int E, int nblk, int nbkt) {
  __shared__ int cur[512];
  int t = threadIdx.x, bid = blockIdx.x;
  for (int r = t; r < nbkt; r += 256) cur[r] = 0;
  __syncthreads();
  int base = bid * EPB;
#pragma unroll
  for (int j = 0; j < EPB / 256; j++) {
    int e = base + j * 256 + t;
    if (e < E) {
      int s = src[e], d = dst[e];
      int b = d >> 8;
      int p = atomicAdd(&cur[b], 1);
      if (p < CAP2)
        binbuf[((size_t)b * nblk + bid) * CAP2 + p] = (uint_t)s | ((uint_t)(d & 255) << 17);
    }
  }
  __syncthreads();
  for (int r = t; r < nbkt; r += 256) {
    int c = cur[r];
    cntmatT[(size_t)r * nblk + bid] = (c < CAP2) ? c : CAP2;
  }
}

// ---------------- k_mid: csr (blocks <nbkt) | prepW2 (32) | gemm1 — 512 threads ----------------
__global__ __launch_bounds__(512) void k_mid(const uint_t* __restrict__ binbuf, const int* __restrict__ cntmatT,
                                             int* __restrict__ esrc, int* __restrict__ deg,
                                             int* __restrict__ offs, float* __restrict__ nrm,
                                             const float* __restrict__ X, const float* __restrict__ W1,
                                             const float* __restrict__ b1, uchar_t* __restrict__ Yf8,
                                             uchar_t* __restrict__ YfC,
                                             const float* __restrict__ W2, ushort_t* __restrict__ Wf2,
                                             int N, int nblk, int nbkt, int GB1m) {
  __shared__ union {
    struct {
      int cnt_s[512];
      int hist[256];
      int cur[256];
      int wsum[4];
      int lsrc[BKT_CAP];
    } c;                           // 36.9 KB (csr role)
    ushort_t Ws[16384];            // 32 KB (gemm role)
  } S;
  int t = threadIdx.x;
  int bid = blockIdx.x;

  if (bid < nbkt) {                // -------- csr --------
    int b = bid;
    if (b == 0 && t == 0) nrm[N] = 0.f;   // tail-clamp slot: scale 0
    int n0 = b << 8;
    int gbase = b * BKT_CAP;
    for (int r = t; r < nblk; r += 512) S.c.cnt_s[r] = cntmatT[(size_t)b * nblk + r];
    if (t < 256) S.c.hist[t] = 0;
    __syncthreads();
    const uint4* seg4 = (const uint4*)(binbuf + (size_t)b * nblk * CAP2);
    int total4 = (nblk * CAP2) >> 2;
    for (int i4 = t; i4 < total4; i4 += 512) {
      int base = i4 << 2;
      int c = S.c.cnt_s[base >> 5];
      int s0 = base & 31;
      if (s0 < c) {
        uint4 v = seg4[i4];
        int nv = c - s0;
        atomicAdd(&S.c.hist[v.x >> 17], 1);
        if (nv > 1) atomicAdd(&S.c.hist[v.y >> 17], 1);
        if (nv > 2) atomicAdd(&S.c.hist[v.z >> 17], 1);
        if (nv > 3) atomicAdd(&S.c.hist[v.w >> 17], 1);
      }
    }
    __syncthreads();
    int lane = t & 63, wv = t >> 6;
    if (t < 256) {
      int h = S.c.hist[t];
      int incl = h;
#pragma unroll
      for (int s = 1; s < 64; s <<= 1) {
        int x = __shfl_up(incl, s, 64);
        if (lane >= s) incl += x;
      }
      if (lane == 63) S.c.wsum[wv] = incl;
      __syncthreads();
      int wbase = 0;
#pragma unroll
      for (int k = 0; k < 4; k++) wbase += (k < wv) ? S.c.wsum[k] : 0;
      int excl = wbase + incl - h;
      S.c.cur[t] = excl;
      int node = n0 + t;
      if (node < N) {
        deg[node] = h;
        offs[node] = gbase + excl;
        nrm[node] = (h > 0) ? rsqrtf((float)h) : 0.f;
      }
    } else {
      __syncthreads();
    }
    __syncthreads();
    int count = S.c.wsum[0] + S.c.wsum[1] + S.c.wsum[2] + S.c.wsum[3];
    for (int i4 = t; i4 < total4; i4 += 512) {
      int base = i4 << 2;
      int c = S.c.cnt_s[base >> 5];
      int s0 = base & 31;
      if (s0 < c) {
        uint4 v = seg4[i4];
        int nv = c - s0;
        { int p = atomicAdd(&S.c.cur[v.x >> 17], 1); S.c.lsrc[p] = (int)(v.x & 0x1ffffu); }
        if (nv > 1) { int p = atomicAdd(&S.c.cur[v.y >> 17], 1); S.c.lsrc[p] = (int)(v.y & 0x1ffffu); }
        if (nv > 2) { int p = atomicAdd(&S.c.cur[v.z >> 17], 1); S.c.lsrc[p] = (int)(v.z & 0x1ffffu); }
        if (nv > 3) { int p = atomicAdd(&S.c.cur[v.w >> 17], 1); S.c.lsrc[p] = (int)(v.w & 0x1ffffu); }
      }
    }
    __syncthreads();
    for (int i = t; i < count; i += 512) esrc[gbase + i] = S.c.lsrc[i];
    return;
  }
  if (bid < nbkt + 32) {           // -------- prepW2 + zero fp8 row N (both buffers) --------
    if (bid == nbkt && t < 8)  ((uint4*)Yf8)[(size_t)N * 8 + t] = make_uint4(0u, 0u, 0u, 0u);
    if (bid == nbkt && t >= 8 && t < 16)
      ((uint4*)YfC)[(size_t)N * 8 + (t - 8)] = make_uint4(0u, 0u, 0u, 0u);
    int idx = (bid - nbkt) * 512 + t;
    int n = idx & 127, k = idx >> 7;
    Wf2[((size_t)(k >> 3) * 128 + n) * 8 + (k & 7)] = f2bf(W2[(size_t)k * 128 + n]);
    return;
  }

  // -------- gemm1: Yf8[r] = fp8( (X[r] @ W1 + b1) * 16 ), 256-row tile, 8 waves --------
  {  // convert W1 (f32 row-major [k][n]) into Ws layout [(q*128+n)*8+j]
    const float4* W4 = (const float4*)W1;
#pragma unroll
    for (int i = 0; i < 8; i++) {
      int idx = i * 512 + t;
      int k = idx >> 5;
      int n0 = (idx & 31) * 4;
      float4 v = W4[idx];
      int qb = k >> 3, j = k & 7;
      S.Ws[((size_t)qb * 128 + n0 + 0) * 8 + j] = f2bf(v.x);
      S.Ws[((size_t)qb * 128 + n0 + 1) * 8 + j] = f2bf(v.y);
      S.Ws[((size_t)qb * 128 + n0 + 2) * 8 + j] = f2bf(v.z);
      S.Ws[((size_t)qb * 128 + n0 + 3) * 8 + j] = f2bf(v.w);
    }
  }
  int r0 = (bid - nbkt - 32) * 256;
  int wave = t >> 6, lane = t & 63;      // wave 0..7
  int ln = lane & 15, quad = lane >> 4;
  int row0 = r0 + wave * 32 + ln;
  int row1 = row0 + 16;
  int cr0 = min(row0, N - 1);
  int cr1 = min(row1, N - 1);

  bf16x8 a0[4], a1[4];
  {
    const float4* Xp = (const float4*)X;
#pragma unroll
    for (int kc = 0; kc < 4; kc++) {
      int q = kc * 4 + quad;
      float4 u0 = Xp[(size_t)cr0 * 32 + q * 2];
      float4 v0 = Xp[(size_t)cr0 * 32 + q * 2 + 1];
      float4 u1 = Xp[(size_t)cr1 * 32 + q * 2];
      float4 v1 = Xp[(size_t)cr1 * 32 + q * 2 + 1];
      a0[kc] = pack8(u0, v0);
      a1[kc] = pack8(u1, v1);
    }
  }
  __syncthreads();

  const bf16x8* Wb = (const bf16x8*)S.Ws;
  f32x4 acc[2][8];
#pragma unroll
  for (int mt = 0; mt < 2; mt++)
#pragma unroll
    for (int ct = 0; ct < 8; ct++) acc[mt][ct] = (f32x4){0.f, 0.f, 0.f, 0.f};

#pragma unroll
  for (int kc = 0; kc < 4; kc++) {
    int q = kc * 4 + quad;
#pragma unroll
    for (int ct = 0; ct < 8; ct++) {
      bf16x8 b = Wb[q * 128 + ct * 16 + ln];
      // swapped operands: lane holds 4 consecutive channels of one node row
      acc[0][ct] = __builtin_amdgcn_mfma_f32_16x16x32_bf16(b, a0[kc], acc[0][ct], 0, 0, 0);
      acc[1][ct] = __builtin_amdgcn_mfma_f32_16x16x32_bf16(b, a1[kc], acc[1][ct], 0, 0, 0);
    }
  }

  int chbase = quad * 4;
  float4 bs[8];
#pragma unroll
  for (int ct = 0; ct < 8; ct++) bs[ct] = *(const float4*)(b1 + ct * 16 + chbase);
  uint_t* Y32 = (uint_t*)Yf8;
  if (row0 < N) {
#pragma unroll
    for (int ct = 0; ct < 8; ct++) {
      f32x4 v = acc[0][ct];
      float x0 = (v[0] + bs[ct].x) * 16.f, x1 = (v[1] + bs[ct].y) * 16.f;
      float x2 = (v[2] + bs[ct].z) * 16.f, x3 = (v[3] + bs[ct].w) * 16.f;
      int w = __builtin_amdgcn_cvt_pk_fp8_f32(x0, x1, 0, false);
      w = __builtin_amdgcn_cvt_pk_fp8_f32(x2, x3, w, true);
      Y32[(size_t)row0 * 32 + ct * 4 + quad] = (uint_t)w;
    }
  }
  if (row1 < N) {
#pragma unroll
    for (int ct = 0; ct < 8; ct++) {
      f32x4 v = acc[1][ct];
      float x0 = (v[0] + bs[ct].x) * 16.f, x1 = (v[1] + bs[ct].y) * 16.f;
      float x2 = (v[2] + bs[ct].z) * 16.f, x3 = (v[3] + bs[ct].w) * 16.f;
      int w = __builtin_amdgcn_cvt_pk_fp8_f32(x0, x1, 0, false);
      w = __builtin_amdgcn_cvt_pk_fp8_f32(x2, x3, w, true);
      Y32[(size_t)row1 * 32 + ct * 4 + quad] = (uint_t)w;
    }
  }
}

// ---------------- agg helpers ----------------
__device__ __forceinline__ void acc16p(f32x2* a, uint4 g) {
  a[0] += __builtin_amdgcn_cvt_pk_f32_fp8((int)g.x, false);
  a[1] += __builtin_amdgcn_cvt_pk_f32_fp8((int)g.x, true);
  a[2] += __builtin_amdgcn_cvt_pk_f32_fp8((int)g.y, false);
  a[3] += __builtin_amdgcn_cvt_pk_f32_fp8((int)g.y, true);
  a[4] += __builtin_amdgcn_cvt_pk_f32_fp8((int)g.z, false);
  a[5] += __builtin_amdgcn_cvt_pk_f32_fp8((int)g.z, true);
  a[6] += __builtin_amdgcn_cvt_pk_f32_fp8((int)g.w, false);
  a[7] += __builtin_amdgcn_cvt_pk_f32_fp8((int)g.w, true);
}
__device__ __forceinline__ void acc16f(f32x2* a, uint4 g, float s) {
  f32x2 sv = {s, s};
  a[0] += __builtin_amdgcn_cvt_pk_f32_fp8((int)g.x, false) * sv;
  a[1] += __builtin_amdgcn_cvt_pk_f32_fp8((int)g.x, true)  * sv;
  a[2] += __builtin_amdgcn_cvt_pk_f32_fp8((int)g.y, false) * sv;
  a[3] += __builtin_amdgcn_cvt_pk_f32_fp8((int)g.y, true)  * sv;
  a[4] += __builtin_amdgcn_cvt_pk_f32_fp8((int)g.z, false) * sv;
  a[5] += __builtin_amdgcn_cvt_pk_f32_fp8((int)g.z, true)  * sv;
  a[6] += __builtin_amdgcn_cvt_pk_f32_fp8((int)g.w, false) * sv;
  a[7] += __builtin_amdgcn_cvt_pk_f32_fp8((int)g.w, true)  * sv;
}
__device__ __forceinline__ uint_t pk2(f32x2 v, float nv) {
  float a = fmaxf(v.x * nv, 0.f);
  float b = fmaxf(v.y * nv, 0.f);
  return (uint_t)f2bf(a) | ((uint_t)f2bf(b) << 16);
}

// ---------------- Fused agg1 + gemm2 ----------------
__global__ __launch_bounds__(256, 5) void k_aggemm(const uint4* __restrict__ hn8, const int* __restrict__ offs,
                                                   const int* __restrict__ deg, const float* __restrict__ nrm,
                                                   const int* __restrict__ esrc, const ushort_t* __restrict__ Wf2,
                                                   const float* __restrict__ b2, uchar_t* __restrict__ YfC,
                                                   int N) {
  __shared__ uint4 Hs[32 * 17];    // 32 rows x (16 chunks + 1 pad) = 8704 B
  int wave = threadIdx.x >> 6, lane = threadIdx.x & 63;
  int sub = lane >> 3, sl = lane & 7;
  int base = blockIdx.x * 32;
  int node = base + wave * 8 + sub;
  bool live = node < N;
  int d  = live ? deg[node] : 0;
  int eb = live ? offs[node] : 0;
  int maxd = d;
  maxd = max(maxd, __shfl_xor(maxd, 8, 64));
  maxd = max(maxd, __shfl_xor(maxd, 16, 64));
  maxd = max(maxd, __shfl_xor(maxd, 32, 64));
  f32x2 A[8] = {};
  f32x2 B[8] = {};
  int it = 0;
  for (; it + 4 <= maxd; it += 4) {
    int x0 = esrc[eb + it];
    int x1 = esrc[eb + it + 1];
    int x2 = esrc[eb + it + 2];
    int x3 = esrc[eb + it + 3];
    x0 = (it < d) ? x0 : N;          // clamped: row N zero, nrm[N]=0
    x1 = (it + 1 < d) ? x1 : N;
    x2 = (it + 2 < d) ? x2 : N;
    x3 = (it + 3 < d) ? x3 : N;
    uint4 g0 = hn8[(size_t)x0 * 8 + sl];
    uint4 g1 = hn8[(size_t)x1 * 8 + sl];
    uint4 g2 = hn8[(size_t)x2 * 8 + sl];
    uint4 g3 = hn8[(size_t)x3 * 8 + sl];
    float s0 = nrm[x0], s1 = nrm[x1], s2 = nrm[x2], s3 = nrm[x3];
    acc16f(A, g0, s0); acc16f(B, g1, s1);
    acc16f(A, g2, s2); acc16f(B, g3, s3);
  }
  for (; it < maxd; it += 2) {
    int x0 = esrc[eb + it];
    int x1 = esrc[eb + it + 1];
    x0 = (it < d) ? x0 : N;
    x1 = (it + 1 < d) ? x1 : N;
    uint4 g0 = hn8[(size_t)x0 * 8 + sl];
    uint4 g1 = hn8[(size_t)x1 * 8 + sl];
    float s0 = nrm[x0], s1 = nrm[x1];
    acc16f(A, g0, s0); acc16f(B, g1, s1);
  }
  float nv = nrm[live ? node : N] * 0.0625f;
  uint4 p0, p1;
  p0.x = pk2(A[0] + B[0], nv); p0.y = pk2(A[1] + B[1], nv);
  p0.z = pk2(A[2] + B[2], nv); p0.w = pk2(A[3] + B[3], nv);
  p1.x = pk2(A[4] + B[4], nv); p1.y = pk2(A[5] + B[5], nv);
  p1.z = pk2(A[6] + B[6], nv); p1.w = pk2(A[7] + B[7], nv);
  int lrow = wave * 8 + sub;
  Hs[lrow * 17 + sl * 2]     = p0;
  Hs[lrow * 17 + sl * 2 + 1] = p1;
  __syncthreads();

  // Phase B: rows base..base+31, wave owns ct = wave*2 + {0,1}
  int ln = lane & 15, quad = lane >> 4;
  const bf16x8* Wb = (const bf16x8*)Wf2;
  f32x4 acc[2][2];
#pragma unroll
  for (int mt = 0; mt < 2; mt++)
#pragma unroll
    for (int c = 0; c < 2; c++) acc[mt][c] = (f32x4){0.f, 0.f, 0.f, 0.f};
#pragma unroll
  for (int kc = 0; kc < 4; kc++) {
    int q = kc * 4 + quad;
    union { uint4 u; bf16x8 b; } a0, a1;
    a0.u = Hs[ln * 17 + q];
    a1.u = Hs[(16 + ln) * 17 + q];
    bf16x8 b0 = Wb[q * 128 + (wave * 2 + 0) * 16 + ln];
    bf16x8 b1 = Wb[q * 128 + (wave * 2 + 1) * 16 + ln];
    acc[0][0] = __builtin_amdgcn_mfma_f32_16x16x32_bf16(b0, a0.b, acc[0][0], 0, 0, 0);
    acc[1][0] = __builtin_amdgcn_mfma_f32_16x16x32_bf16(b0, a1.b, acc[1][0], 0, 0, 0);
    acc[0][1] = __builtin_amdgcn_mfma_f32_16x16x32_bf16(b1, a0.b, acc[0][1], 0, 0, 0);
    acc[1][1] = __builtin_amdgcn_mfma_f32_16x16x32_bf16(b1, a1.b, acc[1][1], 0, 0, 0);
  }
  uint_t* Y32 = (uint_t*)YfC;
#pragma unroll
  for (int mt = 0; mt < 2; mt++) {
    int row = base + mt * 16 + ln;
    int crw = min(row, N);           // nrm has N+1 entries
    float nvr = nrm[crw] * 16.f;
#pragma unroll
    for (int c = 0; c < 2; c++) {
      int ct = wave * 2 + c;
      float4 bs = *(const float4*)(b2 + ct * 16 + quad * 4);
      f32x4 v = acc[mt][c];
      float x0 = (v[0] + bs.x) * nvr, x1 = (v[1] + bs.y) * nvr;
      float x2 = (v[2] + bs.z) * nvr, x3 = (v[3] + bs.w) * nvr;
      int w = __builtin_amdgcn_cvt_pk_fp8_f32(x0, x1, 0, false);
      w = __builtin_amdgcn_cvt_pk_fp8_f32(x2, x3, w, true);
      if (row < N) Y32[(size_t)row * 32 + ct * 4 + quad] = (uint_t)w;
    }
  }
}

// ---------------- Agg layer 2: outb[i] = bf16(relu(nrm_i/16 * sum_e hn2[s])) ----------------
__global__ __launch_bounds__(256) void k_agg2(const uint4* __restrict__ hn8, const int* __restrict__ offs,
                                              const int* __restrict__ deg, const float* __restrict__ nrm,
                                              const int* __restrict__ esrc, uint4* __restrict__ outb, int N) {
  int wave = threadIdx.x >> 6, lane = threadIdx.x & 63;
  int sub = lane >> 3, sl = lane & 7;
  int node = blockIdx.x * 32 + wave * 8 + sub;
  bool live = node < N;
  int d  = live ? deg[node] : 0;
  int eb = live ? offs[node] : 0;
  int maxd = d;
  maxd = max(maxd, __shfl_xor(maxd, 8, 64));
  maxd = max(maxd, __shfl_xor(maxd, 16, 64));
  maxd = max(maxd, __shfl_xor(maxd, 32, 64));
  f32x2 A[8] = {};
  f32x2 B[8] = {};
  int it = 0;
  for (; it + 4 <= maxd; it += 4) {
    int x0 = esrc[eb + it];
    int x1 = esrc[eb + it + 1];
    int x2 = esrc[eb + it + 2];
    int x3 = esrc[eb + it + 3];
    x0 = (it < d) ? x0 : N;
    x1 = (it + 1 < d) ? x1 : N;
    x2 = (it + 2 < d) ? x2 : N;
    x3 = (it + 3 < d) ? x3 : N;
    uint4 g0 = hn8[(size_t)x0 * 8 + sl];
    uint4 g1 = hn8[(size_t)x1 * 8 + sl];
    uint4 g2 = hn8[(size_t)x2 * 8 + sl];
    uint4 g3 = hn8[(size_t)x3 * 8 + sl];
    acc16p(A, g0); acc16p(B, g1);
    acc16p(A, g2); acc16p(B, g3);
  }
  for (; it < maxd; it += 2) {
    int x0 = esrc[eb + it];
    int x1 = esrc[eb + it + 1];
    x0 = (it < d) ? x0 : N;
    x1 = (it + 1 < d) ? x1 : N;
    uint4 g0 = hn8[(size_t)x0 * 8 + sl];
    uint4 g1 = hn8[(size_t)x1 * 8 + sl];
    acc16p(A, g0); acc16p(B, g1);
  }
  if (!live) return;
  float nv = nrm[node] * 0.0625f;
  uint4 p0, p1;
  p0.x = pk2(A[0] + B[0], nv); p0.y = pk2(A[1] + B[1], nv);
  p0.z = pk2(A[2] + B[2], nv); p0.w = pk2(A[3] + B[3], nv);
  p1.x = pk2(A[4] + B[4], nv); p1.y = pk2(A[5] + B[5], nv);
  p1.z = pk2(A[6] + B[6], nv); p1.w = pk2(A[7] + B[7], nv);
  outb[(size_t)node * 16 + sl * 2]     = p0;
  outb[(size_t)node * 16 + sl * 2 + 1] = p1;
}

// ---------------- Head: segmented mean over sorted gidx -> FC(relu) -> dot(Wout)+bout ----------------
__device__ __forceinline__ int lowerb(const int* __restrict__ a, int n, int v) {
  int lo = 0, hi = n;
  while (lo < hi) { int m = (lo + hi) >> 1; if (a[m] < v) lo = m + 1; else hi = m; }
  return lo;
}

__global__ __launch_bounds__(256) void k_head(const ushort_t* __restrict__ h2, const int* __restrict__ gidx,
                                              const float* __restrict__ Wfc, const float* __restrict__ bfc,
                                              const float* __restrict__ Wout, const float* __restrict__ bout,
                                              float* __restrict__ out, int N) {
  __shared__ float partial[4][128];
  __shared__ float pv[128];
  __shared__ float fcp[2][128];
  __shared__ float red[128];
  __shared__ int segb[2];
  int g = blockIdx.x, t = threadIdx.x;
  int wave = t >> 6, lane = t & 63;
  if (t == 0)  segb[0] = lowerb(gidx, N, g);
  if (t == 64) segb[1] = lowerb(gidx, N, g + 1);
  __syncthreads();
  int lo = segb[0], hi = segb[1];
  int q = lane & 15;
  int r4 = lane >> 4;
  const uint4* h4 = (const uint4*)h2;
  f32x2 A[4] = {};
  for (int i = lo + wave * 4 + r4; i < hi; i += 16) {
    uint4 v = h4[(size_t)i * 16 + q];
    A[0] += (f32x2){__uint_as_float(v.x << 16), __uint_as_float(v.x & 0xffff0000u)};
    A[1] += (f32x2){__uint_as_float(v.y << 16), __uint_as_float(v.y & 0xffff0000u)};
    A[2] += (f32x2){__uint_as_float(v.z << 16), __uint_as_float(v.z & 0xffff0000u)};
    A[3] += (f32x2){__uint_as_float(v.w << 16), __uint_as_float(v.w & 0xffff0000u)};
  }
#pragma unroll
  for (int k = 0; k < 4; k++) {
    A[k].x += __shfl_xor(A[k].x, 16, 64); A[k].y += __shfl_xor(A[k].y, 16, 64);
    A[k].x += __shfl_xor(A[k].x, 32, 64); A[k].y += __shfl_xor(A[k].y, 32, 64);
  }
  if (lane < 16) {
    partial[wave][q * 8 + 0] = A[0].x; partial[wave][q * 8 + 1] = A[0].y;
    partial[wave][q * 8 + 2] = A[1].x; partial[wave][q * 8 + 3] = A[1].y;
    partial[wave][q * 8 + 4] = A[2].x; partial[wave][q * 8 + 5] = A[2].y;
    partial[wave][q * 8 + 6] = A[3].x; partial[wave][q * 8 + 7] = A[3].y;
  }
  __syncthreads();
  if (t < 128) {
    float c = (float)(hi - lo); if (c < 1.f) c = 1.f;
    float s = (partial[0][t] + partial[1][t]) + (partial[2][t] + partial[3][t]);
    pv[t] = s / c;
  }
  __syncthreads();
  int col = t & 127, half = t >> 7;
  float acc = (half == 0) ? bfc[col] : 0.f;
  const float* Wc = Wfc + (size_t)half * 64 * 128 + col;
#pragma unroll 8
  for (int k = 0; k < 64; k++) acc += pv[half * 64 + k] * Wc[k * 128];
  fcp[half][col] = acc;
  __syncthreads();
  if (t < 128) {
    float a = fmaxf(fcp[0][t] + fcp[1][t], 0.f);
    red[t] = a * Wout[t];
  }
  __syncthreads();
  if (t < 64) {
    float v2 = red[t] + red[t + 64];
#pragma unroll
    for (int s = 32; s > 0; s >>= 1) v2 += __shfl_xor(v2, s, 64);
    if (t == 0) out[g] = v2 + bout[0];
  }
}

// ---------------- launch ----------------

extern "C" void kernel_launch(void* const* d_in, const int* in_sizes, int n_in,
                              void* d_out, int out_size, void* d_ws, size_t ws_size,
                              hipStream_t stream) {
  const float* X    = (const float*)d_in[0];
  const int*   adj  = (const int*)d_in[1];
  const int*   gidx = (const int*)d_in[2];
  // d_in[3] = is_training (ignored; dropout rate is 0)
  const float* W1   = (const float*)d_in[4];
  const float* b1   = (const float*)d_in[5];
  const float* W2   = (const float*)d_in[6];
  const float* b2   = (const float*)d_in[7];
  const float* Wfc  = (const float*)d_in[8];
  const float* bfc  = (const float*)d_in[9];
  const float* Wout = (const float*)d_in[10];
  const float* bout = (const float*)d_in[11];
  (void)n_in; (void)ws_size;

  const int N = in_sizes[2];        // 100000
  const int E = in_sizes[1] / 2;    // 1600000
  const int G = out_size;           // 1024 (OUT=1)
  const int* srcv = adj;
  const int* dstv = adj + E;
  const int nbkt = (N + 255) >> 8;            // 391 buckets of 256 nodes
  const int nblk = (E + EPB - 1) / EPB;       // 391 bin blocks
  const int GB1m = (N + 255) / 256;           // 391 gemm1 blocks (256-row tiles)

  char* w = (char*)d_ws;
  size_t off = 0;
  auto alloc = [&](size_t bytes) -> void* {
    void* p = (void*)(w + off);
    off += (bytes + 255) & ~(size_t)255;
    return p;
  };
  uchar_t*  bufA  = (uchar_t*)alloc((size_t)(N + 1) * 128);                // hn1 fp8 + zero row N
  uchar_t*  bufC  = (uchar_t*)alloc((size_t)(N + 1) * 128);                // hn2 fp8 + zero row N
  ushort_t* bufB  = (ushort_t*)alloc((size_t)N * 128 * sizeof(ushort_t));  // h2 (bf16)
  float*    nrm   = (float*)alloc((size_t)(N + 1) * sizeof(float));        // +1: nrm[N]=0
  int*      deg   = (int*)alloc((size_t)N * sizeof(int));
  int*      offs  = (int*)alloc((size_t)N * sizeof(int));
  int*      esrc  = (int*)alloc(((size_t)nbkt * BKT_CAP + BKT_CAP) * sizeof(int));  // + slack
  uint_t*   binb  = (uint_t*)alloc((size_t)nbkt * nblk * CAP2 * sizeof(uint_t));
  int*      cmatT = (int*)alloc((size_t)nbkt * nblk * sizeof(int));        // bucket-major
  ushort_t* Wf2   = (ushort_t*)alloc((size_t)128 * 128 * sizeof(ushort_t));

  // stage 1: bin alone (csr's only dependency)
  k_bin<<<nblk, 256, 0, stream>>>(srcv, dstv, binb, cmatT, E, nblk, nbkt);
  // stage 2: csr | prepW2 | gemm1 overlapped (csr blocks dispatched first)
  k_mid<<<nbkt + 32 + GB1m, 512, 0, stream>>>(binb, cmatT, esrc, deg, offs, nrm,
                                              X, W1, b1, bufA, bufC, W2, Wf2,
                                              N, nblk, nbkt, GB1m);

  const int aggGrid = (N + 31) / 32;
  // fused agg1 + gemm2: bufA -> (h1 in LDS) -> bufC (fp8)
  k_aggemm<<<aggGrid, 256, 0, stream>>>((const uint4*)bufA, offs, deg, nrm, esrc,
                                        Wf2, b2, bufC, N);
  // agg2: bufC -> bufB (h2 bf16)
  k_agg2<<<aggGrid, 256, 0, stream>>>((const uint4*)bufC, offs, deg, nrm, esrc, (uint4*)bufB, N);
  k_head<<<G, 256, 0, stream>>>(bufB, gidx, Wfc, bfc, Wout, bout, (float*)d_out, N);
}